// Round 14
// baseline (123.919 us; speedup 1.0000x reference)
//
#include <hip/hip_runtime.h>
#include <cstdint>

typedef unsigned short u16;
typedef unsigned int u32;
typedef float f32x4 __attribute__((ext_vector_type(4)));
typedef __bf16 bf16x8 __attribute__((ext_vector_type(8)));
typedef __bf16 bf16x4 __attribute__((ext_vector_type(4)));
typedef u16 u16x8 __attribute__((ext_vector_type(8)));

#define B_ 2
#define S_ 2048
#define NX_ 1024
#define NH_ 16
#define HD_ 64
#define T3_ 3072
#define M_ 4096          // B_*S_ tokens
#define SCL 0.18033688011112042f   // 0.125 * log2(e); folded into Q at GEMM1 epilogue

__device__ __forceinline__ u16 bfbits(float f) {
    __bf16 h = (__bf16)f;            // native cvt (RNE), pairs to v_cvt_pk_bf16_f32
    return __builtin_bit_cast(u16, h);
}

__device__ __forceinline__ void gload_lds16(const void* g, void* l) {
    auto gp = reinterpret_cast<const __attribute__((address_space(1))) u32*>(
        reinterpret_cast<uintptr_t>(g));
    auto lp = reinterpret_cast<__attribute__((address_space(3))) u32*>(
        reinterpret_cast<uintptr_t>(l));
    __builtin_amdgcn_global_load_lds(gp, lp, 16, 0, 0);
}

// ---------------- convert f32 -> bf16, vectorized ----------------
__global__ __launch_bounds__(256) void cvt_bf16_kernel(const float* __restrict__ X,
                                                       u16* __restrict__ Y) {
    int i = (blockIdx.x * 256 + threadIdx.x) * 4;
    float4 v = *reinterpret_cast<const float4*>(X + i);
    bf16x4 o;
    o[0] = (__bf16)v.x; o[1] = (__bf16)v.y; o[2] = (__bf16)v.z; o[3] = (__bf16)v.w;
    *reinterpret_cast<bf16x4*>(Y + i) = o;
}

// ---------------- transpose + convert: W[K][N] f32 -> WT[N][K] bf16 ----------------
__global__ __launch_bounds__(256) void transpose_cvt_kernel(const float* __restrict__ W,
                                                            u16* __restrict__ WT,
                                                            int K, int N) {
    __shared__ float tile[32][33];
    int nbx = N >> 5;
    int nb = (blockIdx.x % nbx) << 5;
    int kb = (blockIdx.x / nbx) << 5;
    int tx = threadIdx.x & 31, ty = threadIdx.x >> 5;
#pragma unroll
    for (int i = 0; i < 32; i += 8)
        tile[ty + i][tx] = W[(size_t)(kb + ty + i) * N + nb + tx];
    __syncthreads();
#pragma unroll
    for (int i = 0; i < 32; i += 8)
        WT[(size_t)(nb + ty + i) * K + kb + tx] = bfbits(tile[tx][ty + i]);
}

// ---------------- 128^2 bf16 GEMM, SINGLE-buffer + chunk-XOR swizzle ----------------
// m97-style: 32KB LDS -> 4-5 blocks/CU; per-tile drain hidden by co-resident blocks
// (m114 overlap). 2D XCD superblocks (bn-fast; per-XCD panel set ~L2-sized).
// Columns < qcols scaled by SCL; columns >= vcol0 written transposed: Vt[g][d][s].
#define BM 128
#define BN 128
#define BK 64
__global__ __launch_bounds__(256) void gemm_bt_kernel(const u16* __restrict__ A,
                                                      const u16* __restrict__ Bt,
                                                      const float* __restrict__ bias,
                                                      u16* __restrict__ Cb,
                                                      float* __restrict__ Cf,
                                                      u16* __restrict__ Vt,
                                                      int vcol0, int qcols,
                                                      int gx, int sbm, int sbn,
                                                      int M, int N, int K) {
    __shared__ u16 a_lds[BM * BK];
    __shared__ u16 b_lds[BN * BK];
    int orig = blockIdx.x;
    int xcd = orig & 7, li = orig >> 3;
    int bm = (xcd % gx) * sbm + li / sbn;
    int bn = (xcd / gx) * sbn + li % sbn;
    int t = threadIdx.x;
    int w = t >> 6, l = t & 63, lg = l >> 4, lr = l & 15;
    int wr = w >> 1, wc = w & 1;
    const u16* Abase = A + (size_t)bm * BM * K;
    const u16* Bbase = Bt + (size_t)bn * BN * K;

    f32x4 zero4 = {0.f, 0.f, 0.f, 0.f};
    f32x4 acc[4][4];
#pragma unroll
    for (int m = 0; m < 4; ++m)
#pragma unroll
        for (int n = 0; n < 4; ++n) acc[m][n] = zero4;

    int nkt = K / BK;
    for (int kt = 0; kt < nkt; ++kt) {
        // stage tile kt: linear LDS dest, inverse-swizzled global source chunk
#pragma unroll
        for (int it = 0; it < 4; ++it) {
            int idx = it * 256 + t;              // 0..1023 = 128 rows x 8 chunks
            int row = idx >> 3, ck = idx & 7;
            int cds = ck ^ (row & 7);            // data chunk stored in this slot
            int ubase = (it * 256 + w * 64) * 8; // u16 units, wave-uniform
            gload_lds16(Abase + (size_t)row * K + kt * BK + cds * 8, &a_lds[ubase]);
            gload_lds16(Bbase + (size_t)row * K + kt * BK + cds * 8, &b_lds[ubase]);
        }
        __syncthreads();

#pragma unroll
        for (int ks = 0; ks < 2; ++ks) {
            int ck = (ks * 4 + lg) ^ (lr & 7);   // row&7 == lr&7 for all fragment rows
            bf16x8 af[4], bf[4];
#pragma unroll
            for (int m = 0; m < 4; ++m)
                af[m] = *reinterpret_cast<const bf16x8*>(
                    &a_lds[(wr * 64 + m * 16 + lr) * BK + ck * 8]);
#pragma unroll
            for (int n = 0; n < 4; ++n)
                bf[n] = *reinterpret_cast<const bf16x8*>(
                    &b_lds[(wc * 64 + n * 16 + lr) * BK + ck * 8]);
            __builtin_amdgcn_s_setprio(1);
#pragma unroll
            for (int m = 0; m < 4; ++m)
#pragma unroll
                for (int n = 0; n < 4; ++n)
                    acc[m][n] = __builtin_amdgcn_mfma_f32_16x16x32_bf16(
                        af[m], bf[n], acc[m][n], 0, 0, 0);
            __builtin_amdgcn_s_setprio(0);
        }
        __syncthreads();   // all waves done reading before next stage overwrites
    }

#pragma unroll
    for (int n = 0; n < 4; ++n) {
        int col0 = bn * BN + wc * 64 + n * 16;
        int col = col0 + lr;
        float bv = bias[col];
        float sc = (col0 < qcols) ? SCL : 1.0f;   // pre-scale Q columns
        bool isv = (Vt != nullptr) && (col0 >= vcol0);
#pragma unroll
        for (int m = 0; m < 4; ++m) {
            int row0 = bm * BM + wr * 64 + m * 16 + lg * 4;
            if (isv) {
                int nv = col - vcol0, hh = nv >> 6, dd = nv & 63;
                int bb = row0 >> 11, ss = row0 & 2047;
                bf16x4 pk;
#pragma unroll
                for (int r = 0; r < 4; ++r) pk[r] = (__bf16)(acc[m][n][r] + bv);
                *reinterpret_cast<bf16x4*>(
                    Vt + (((size_t)(bb * 16 + hh) * 64 + dd) << 11) + ss) = pk;
            } else {
#pragma unroll
                for (int r = 0; r < 4; ++r) {
                    float v = (acc[m][n][r] + bv) * sc;
                    if (Cf) Cf[(size_t)(row0 + r) * N + col] = v;
                    else    Cb[(size_t)(row0 + r) * N + col] = bfbits(v);
                }
            }
        }
    }
}

// ---------------- flash attention (R12, proven): 8-wave blocks, q-tile 128 ----------------
// 512 blocks x 512 thr. Each staged K/V tile feeds 8 wave-tiles. Waves 0-3 skip the
// final diagonal tile (kt<=tw). Q pre-scaled by SCL in GEMM1 -> softmax in log2 domain.
__global__ __launch_bounds__(512) void attn_kernel(const u16* __restrict__ qkv,
                                                   const u16* __restrict__ Vt,
                                                   u16* __restrict__ outa) {
    __shared__ u16 k_lds[2][4096];   // [k 64][d 64], chunk16-swizzled ^ (row&7)
    __shared__ u16 v_lds[2][4096];   // [d 64][k 64], chunk16-swizzled ^ (row&7)
    __shared__ u16 p_lds[8192];      // [q 128][k 64], chunk16-swizzled ^ (row&7)

    int bid = blockIdx.x;
    int g = bid & 31;                // same g -> same XCD (stride 32 ≡ 0 mod 8)
    int j = bid >> 5;                // 0..15
    int qt = (j < 8) ? (15 - j) : (j - 8);   // CU pairs (15-k, k): uniform 36 tiles/CU
    int b = g >> 4, h = g & 15;
    int t = threadIdx.x, w = t >> 6, l = t & 63, lg = l >> 4, lr = l & 15;
    const u16* base = qkv + (size_t)b * S_ * T3_;
    const u16* vbase = Vt + (size_t)g * 64 * S_;
    int prow = w * 16 + lr;          // local P row (wave-private slab, 0..127)
    int qb = qt * 128;
    int qrow = qb + w * 16 + lr;     // this lane's q (column of S^T)

    // staging: 512 threads cover one 64x64 tile in ONE pass
    int srow = w * 8 + (l >> 3);
    auto stage = [&](int kt2, int bs) {
        int kb2 = kt2 * 64;
        int ckg = (l & 7) ^ (srow & 7);          // pre-swizzled global chunk
        gload_lds16(base + (size_t)(kb2 + srow) * T3_ + NX_ + h * 64 + ckg * 8,
                    &k_lds[bs][w * 512]);
        gload_lds16(vbase + (size_t)srow * S_ + kb2 + ckg * 8,
                    &v_lds[bs][w * 512]);
    };

    f32x4 zero4 = {0.f, 0.f, 0.f, 0.f};

    bf16x8 qf[2];
#pragma unroll
    for (int ks = 0; ks < 2; ++ks)
        qf[ks] = *reinterpret_cast<const bf16x8*>(
            base + (size_t)qrow * T3_ + h * 64 + ks * 32 + lg * 8);

    f32x4 oacc[4];
#pragma unroll
    for (int dc = 0; dc < 4; ++dc) oacc[dc] = zero4;
    float mrun = -1e30f, lrun = 0.f;
    int nkt = 2 * qt + 2;            // block-uniform kv range
    int tw = 2 * qt + (w >> 2);      // this wave's last needed kv-tile

    stage(0, 0);
    __syncthreads();

    for (int kt = 0; kt < nkt; ++kt) {
        int cur = kt & 1;
        if (kt + 1 < nkt) stage(kt + 1, cur ^ 1);   // issue early; drains at end barrier

        if (kt <= tw) {
            int kb = kt * 64;
            // S^T = K Q^T : lane holds S[k = kb+kn*16+lg*4+r][q = qrow] (log2 units)
            f32x4 sacc[4];
#pragma unroll
            for (int kn = 0; kn < 4; ++kn) sacc[kn] = zero4;
            __builtin_amdgcn_s_setprio(1);
#pragma unroll
            for (int ks = 0; ks < 2; ++ks) {
#pragma unroll
                for (int kn = 0; kn < 4; ++kn) {
                    bf16x8 kf = *reinterpret_cast<const bf16x8*>(
                        &k_lds[cur][(kn * 16 + lr) * 64 + (((ks * 4 + lg) ^ (lr & 7)) * 8)]);
                    sacc[kn] = __builtin_amdgcn_mfma_f32_16x16x32_bf16(
                        kf, qf[ks], sacc[kn], 0, 0, 0);
                }
            }
            __builtin_amdgcn_s_setprio(0);

            if (kt == tw) {   // diagonal tile: causal mask (kv > q)
#pragma unroll
                for (int kn = 0; kn < 4; ++kn)
#pragma unroll
                    for (int r = 0; r < 4; ++r)
                        if (kb + kn * 16 + lg * 4 + r > qrow) sacc[kn][r] = -1e30f;
            }

            // in-register online softmax (log2 domain)
            float mx = -1e30f;
#pragma unroll
            for (int kn = 0; kn < 4; ++kn) {
                float a0 = fmaxf(sacc[kn][0], sacc[kn][1]);
                float a1 = fmaxf(sacc[kn][2], sacc[kn][3]);
                mx = fmaxf(mx, fmaxf(a0, a1));
            }
            mx = fmaxf(mx, __shfl_xor(mx, 16));
            mx = fmaxf(mx, __shfl_xor(mx, 32));

            bool noresc = __all(mx <= mrun + 1.5f);   // defer-max: P <= 2^1.5 = 2.83
            float mnew = noresc ? mrun : fmaxf(mrun, mx);

            float rs = 0.f;
#pragma unroll
            for (int kn = 0; kn < 4; ++kn)
#pragma unroll
                for (int r = 0; r < 4; ++r) {
                    float pv = exp2f(sacc[kn][r] - mnew);
                    sacc[kn][r] = pv;
                    rs += pv;
                }
            rs += __shfl_xor(rs, 16);
            rs += __shfl_xor(rs, 32);

            if (noresc) {
                lrun += rs;
            } else {
                float fsc = exp2f(mrun - mnew);
                mrun = mnew;
                lrun = lrun * fsc + rs;
                float f0 = __shfl(fsc, lg * 4 + 0);
                float f1 = __shfl(fsc, lg * 4 + 1);
                float f2 = __shfl(fsc, lg * 4 + 2);
                float f3 = __shfl(fsc, lg * 4 + 3);
#pragma unroll
                for (int dc = 0; dc < 4; ++dc) {
                    oacc[dc][0] *= f0; oacc[dc][1] *= f1;
                    oacc[dc][2] *= f2; oacc[dc][3] *= f3;
                }
            }

            // P -> LDS, packed 8B writes, swizzled (wave-private slab: no barrier needed)
#pragma unroll
            for (int kn = 0; kn < 4; ++kn) {
                bf16x4 pb;
                pb[0] = (__bf16)sacc[kn][0]; pb[1] = (__bf16)sacc[kn][1];
                pb[2] = (__bf16)sacc[kn][2]; pb[3] = (__bf16)sacc[kn][3];
                int byteoff = prow * 128 + (((2 * kn + (lg >> 1)) ^ (prow & 7)) * 16) + (lg & 1) * 8;
                *reinterpret_cast<bf16x4*>(reinterpret_cast<char*>(p_lds) + byteoff) = pb;
            }

            // O += P V  (A = P rows from LDS, B = Vt rows)
            __builtin_amdgcn_s_setprio(1);
#pragma unroll
            for (int ks = 0; ks < 2; ++ks) {
                bf16x8 pf = *reinterpret_cast<const bf16x8*>(
                    reinterpret_cast<char*>(p_lds) + prow * 128 + (((ks * 4 + lg) ^ (prow & 7)) * 16));
#pragma unroll
                for (int dc = 0; dc < 4; ++dc) {
                    bf16x8 vf = *reinterpret_cast<const bf16x8*>(
                        &v_lds[cur][(dc * 16 + lr) * 64 + (((ks * 4 + lg) ^ (lr & 7)) * 8)]);
                    oacc[dc] = __builtin_amdgcn_mfma_f32_16x16x32_bf16(
                        pf, vf, oacc[dc], 0, 0, 0);
                }
            }
            __builtin_amdgcn_s_setprio(0);
        }
        __syncthreads();   // single barrier/tile: k/v_lds[cur] reads done before restage
    }

    // epilogue: O /= l ; store bf16 [token][h*64+d]
    float inv = 1.f / lrun;
    float i0 = __shfl(inv, lg * 4 + 0);
    float i1 = __shfl(inv, lg * 4 + 1);
    float i2 = __shfl(inv, lg * 4 + 2);
    float i3 = __shfl(inv, lg * 4 + 3);
    u16* ob = outa + (size_t)b * S_ * NX_;
#pragma unroll
    for (int r = 0; r < 4; ++r) {
        float ir = (r == 0) ? i0 : (r == 1) ? i1 : (r == 2) ? i2 : i3;
        int row = qb + w * 16 + lg * 4 + r;
#pragma unroll
        for (int dc = 0; dc < 4; ++dc)
            ob[(size_t)row * NX_ + h * 64 + dc * 16 + lr] = bfbits(oacc[dc][r] * ir);
    }
}

extern "C" void kernel_launch(void* const* d_in, const int* in_sizes, int n_in,
                              void* d_out, int out_size, void* d_ws, size_t ws_size,
                              hipStream_t stream) {
    const float* x        = (const float*)d_in[0];
    const float* c_attn_w = (const float*)d_in[1];
    const float* c_attn_b = (const float*)d_in[2];
    const float* c_proj_w = (const float*)d_in[3];
    const float* c_proj_b = (const float*)d_in[4];
    float* out = (float*)d_out;

    u16* xb     = (u16*)d_ws;                         // [4096][1024] bf16  (8 MB)
    u16* wqkvT  = xb + (size_t)M_ * NX_;              // [3072][1024] bf16  (6 MB)
    u16* wprojT = wqkvT + (size_t)T3_ * NX_;          // [1024][1024] bf16  (2 MB)
    u16* qkv    = wprojT + (size_t)NX_ * NX_;         // [4096][3072] bf16  (24 MB; V part unused)
    u16* attno  = xb;                                 // reuse xb after GEMM1 (8 MB)
    u16* Vtp    = (u16*)d_out;                        // scratch: Vt 8 MB inside 16 MB out;
                                                      // fully overwritten by GEMM2 at the end

    // 1) x -> bf16
    cvt_bf16_kernel<<<(M_ * NX_) / 1024, 256, 0, stream>>>(x, xb);
    // 2) weights -> transposed bf16
    transpose_cvt_kernel<<<(T3_ / 32) * (NX_ / 32), 256, 0, stream>>>(c_attn_w, wqkvT, NX_, T3_);
    transpose_cvt_kernel<<<(NX_ / 32) * (NX_ / 32), 256, 0, stream>>>(c_proj_w, wprojT, NX_, NX_);
    // 3) qkv = x @ c_attn_w + b (bf16, Q pre-scaled); V-part -> Vtp transposed.
    //    2D superblocks: 32x24 grid -> gx=4, sbm=8, sbn=12
    gemm_bt_kernel<<<(M_ / BM) * (T3_ / BN), 256, 0, stream>>>(
        xb, wqkvT, c_attn_b, qkv, nullptr, Vtp, 2 * NX_, NX_, 4, 8, 12, M_, T3_, NX_);
    // 4) attention (8-wave blocks, q-tile 128, 512 blocks)
    attn_kernel<<<512, 512, 0, stream>>>(qkv, Vtp, attno);
    // 5) out = attn @ c_proj_w + b (f32). 32x8 grid -> gx=4, sbm=8, sbn=4
    gemm_bt_kernel<<<(M_ / BM) * (NX_ / BN), 256, 0, stream>>>(
        attno, wprojT, c_proj_b, nullptr, out, nullptr, 0, 0, 4, 8, 4, M_, NX_, NX_);
}

// Round 15
// 115.147 us; speedup vs baseline: 1.0762x; 1.0762x over previous
//
#include <hip/hip_runtime.h>
#include <cstdint>

typedef unsigned short u16;
typedef unsigned int u32;
typedef float f32x4 __attribute__((ext_vector_type(4)));
typedef __bf16 bf16x8 __attribute__((ext_vector_type(8)));
typedef __bf16 bf16x4 __attribute__((ext_vector_type(4)));
typedef u16 u16x8 __attribute__((ext_vector_type(8)));

#define B_ 2
#define S_ 2048
#define NX_ 1024
#define NH_ 16
#define HD_ 64
#define T3_ 3072
#define M_ 4096          // B_*S_ tokens
#define SCL 0.18033688011112042f   // 0.125 * log2(e); folded into Q at GEMM1 epilogue

__device__ __forceinline__ u16 bfbits(float f) {
    __bf16 h = (__bf16)f;            // native cvt (RNE), pairs to v_cvt_pk_bf16_f32
    return __builtin_bit_cast(u16, h);
}

__device__ __forceinline__ void gload_lds16(const void* g, void* l) {
    auto gp = reinterpret_cast<const __attribute__((address_space(1))) u32*>(
        reinterpret_cast<uintptr_t>(g));
    auto lp = reinterpret_cast<__attribute__((address_space(3))) u32*>(
        reinterpret_cast<uintptr_t>(l));
    __builtin_amdgcn_global_load_lds(gp, lp, 16, 0, 0);
}

// ---------------- fused prep: x->bf16 + both weight transposes, one launch ----------------
// blocks [0,4096): cvt x; [4096,7168): transpose c_attn_w; [7168,8192): transpose c_proj_w.
// Branch is block-uniform; the three jobs touch disjoint tensors.
__global__ __launch_bounds__(256) void prep_kernel(const float* __restrict__ x,
                                                   u16* __restrict__ xb,
                                                   const float* __restrict__ w1,
                                                   u16* __restrict__ w1t,
                                                   const float* __restrict__ w2,
                                                   u16* __restrict__ w2t) {
    __shared__ float tile[32][33];
    int bid = blockIdx.x;
    if (bid < 4096) {                 // vectorized f32 -> bf16 convert of x
        int i = (bid * 256 + threadIdx.x) * 4;
        float4 v = *reinterpret_cast<const float4*>(x + i);
        bf16x4 o;
        o[0] = (__bf16)v.x; o[1] = (__bf16)v.y; o[2] = (__bf16)v.z; o[3] = (__bf16)v.w;
        *reinterpret_cast<bf16x4*>(xb + i) = o;
        return;
    }
    const float* W; u16* WT; int N, lb;
    if (bid < 4096 + 3072) { W = w1; WT = w1t; N = T3_; lb = bid - 4096; }
    else                   { W = w2; WT = w2t; N = NX_; lb = bid - 7168; }
    const int K = NX_;
    int nbx = N >> 5;
    int nb = (lb % nbx) << 5;
    int kb = (lb / nbx) << 5;
    int tx = threadIdx.x & 31, ty = threadIdx.x >> 5;
#pragma unroll
    for (int i = 0; i < 32; i += 8)
        tile[ty + i][tx] = W[(size_t)(kb + ty + i) * N + nb + tx];
    __syncthreads();
#pragma unroll
    for (int i = 0; i < 32; i += 8)
        WT[(size_t)(nb + ty + i) * K + kb + tx] = bfbits(tile[tx][ty + i]);
}

// ---------------- 128^2 bf16 GEMM, double-buffered prefetch + chunk-XOR swizzle ----------------
// C[M][N] = A[M][K] * Bt[N][K]^T + bias.  Columns < qcols are scaled by SCL
// (pre-scales Q so attention's softmax runs in log2 domain with no per-element mul).
// If Vt!=null, columns >= vcol0 are written transposed per-head: Vt[g][d][s].
#define BM 128
#define BN 128
#define BK 64
__global__ __launch_bounds__(256) void gemm_bt_kernel(const u16* __restrict__ A,
                                                      const u16* __restrict__ Bt,
                                                      const float* __restrict__ bias,
                                                      u16* __restrict__ Cb,
                                                      float* __restrict__ Cf,
                                                      u16* __restrict__ Vt,
                                                      int vcol0, int qcols,
                                                      int M, int N, int K) {
    __shared__ u16 a_lds[2][BM * BK];
    __shared__ u16 b_lds[2][BN * BK];
    int nbn = N / BN;
    int nwg = gridDim.x;
    int orig = blockIdx.x;
    int wg = (orig & 7) * (nwg >> 3) + (orig >> 3);   // XCD-contiguous chunks
    int bm = wg / nbn, bn = wg % nbn;
    int t = threadIdx.x;
    int w = t >> 6, l = t & 63, lg = l >> 4, lr = l & 15;
    int wr = w >> 1, wc = w & 1;
    const u16* Abase = A + (size_t)bm * BM * K;
    const u16* Bbase = Bt + (size_t)bn * BN * K;

    f32x4 zero4 = {0.f, 0.f, 0.f, 0.f};
    f32x4 acc[4][4];
#pragma unroll
    for (int m = 0; m < 4; ++m)
#pragma unroll
        for (int n = 0; n < 4; ++n) acc[m][n] = zero4;

    auto stage = [&](int kt, int bs) {
#pragma unroll
        for (int it = 0; it < 4; ++it) {
            int idx = it * 256 + t;              // 0..1023 = 128 rows x 8 chunks
            int row = idx >> 3, ck = idx & 7;
            int cds = ck ^ (row & 7);            // data chunk stored in this slot
            int ubase = (it * 256 + w * 64) * 8; // u16 units, wave-uniform
            gload_lds16(Abase + (size_t)row * K + kt * BK + cds * 8, &a_lds[bs][ubase]);
            gload_lds16(Bbase + (size_t)row * K + kt * BK + cds * 8, &b_lds[bs][ubase]);
        }
    };

    stage(0, 0);
    __syncthreads();

    int nkt = K / BK;
    for (int kt = 0; kt < nkt; ++kt) {
        int cur = kt & 1;
        if (kt + 1 < nkt) stage(kt + 1, cur ^ 1);   // prefetch into other buffer

#pragma unroll
        for (int ks = 0; ks < 2; ++ks) {
            int ck = (ks * 4 + lg) ^ (lr & 7);      // row&7 == lr&7 for all fragment rows
            bf16x8 af[4], bf[4];
#pragma unroll
            for (int m = 0; m < 4; ++m)
                af[m] = *reinterpret_cast<const bf16x8*>(
                    &a_lds[cur][(wr * 64 + m * 16 + lr) * BK + ck * 8]);
#pragma unroll
            for (int n = 0; n < 4; ++n)
                bf[n] = *reinterpret_cast<const bf16x8*>(
                    &b_lds[cur][(wc * 64 + n * 16 + lr) * BK + ck * 8]);
            __builtin_amdgcn_s_setprio(1);
#pragma unroll
            for (int m = 0; m < 4; ++m)
#pragma unroll
                for (int n = 0; n < 4; ++n)
                    acc[m][n] = __builtin_amdgcn_mfma_f32_16x16x32_bf16(
                        af[m], bf[n], acc[m][n], 0, 0, 0);
            __builtin_amdgcn_s_setprio(0);
        }
        __syncthreads();   // one barrier/tile: drains prefetch (amortized)
    }

#pragma unroll
    for (int n = 0; n < 4; ++n) {
        int col0 = bn * BN + wc * 64 + n * 16;
        int col = col0 + lr;
        float bv = bias[col];
        float sc = (col0 < qcols) ? SCL : 1.0f;   // pre-scale Q columns
        bool isv = (Vt != nullptr) && (col0 >= vcol0);
#pragma unroll
        for (int m = 0; m < 4; ++m) {
            int row0 = bm * BM + wr * 64 + m * 16 + lg * 4;
            if (isv) {
                int nv = col - vcol0, hh = nv >> 6, dd = nv & 63;
                int bb = row0 >> 11, ss = row0 & 2047;
                bf16x4 pk;
#pragma unroll
                for (int r = 0; r < 4; ++r) pk[r] = (__bf16)(acc[m][n][r] + bv);
                *reinterpret_cast<bf16x4*>(
                    Vt + (((size_t)(bb * 16 + hh) * 64 + dd) << 11) + ss) = pk;
            } else {
#pragma unroll
                for (int r = 0; r < 4; ++r) {
                    float v = (acc[m][n][r] + bv) * sc;
                    if (Cf) Cf[(size_t)(row0 + r) * N + col] = v;
                    else    Cb[(size_t)(row0 + r) * N + col] = bfbits(v);
                }
            }
        }
    }
}

// ---------------- flash attention (R12 best): 8-wave blocks, q-tile 128 ----------------
// 512 blocks x 512 thr. Each staged K/V tile feeds 8 wave-tiles. Waves 0-3 skip the
// final diagonal tile (kt<=tw). Q pre-scaled by SCL in GEMM1 -> softmax in log2 domain.
__global__ __launch_bounds__(512) void attn_kernel(const u16* __restrict__ qkv,
                                                   const u16* __restrict__ Vt,
                                                   u16* __restrict__ outa) {
    __shared__ u16 k_lds[2][4096];   // [k 64][d 64], chunk16-swizzled ^ (row&7)
    __shared__ u16 v_lds[2][4096];   // [d 64][k 64], chunk16-swizzled ^ (row&7)
    __shared__ u16 p_lds[8192];      // [q 128][k 64], chunk16-swizzled ^ (row&7)

    int bid = blockIdx.x;
    int g = bid & 31;                // same g -> same XCD (stride 32 ≡ 0 mod 8)
    int j = bid >> 5;                // 0..15
    int qt = (j < 8) ? (15 - j) : (j - 8);   // CU pairs (15-k, k): uniform 36 tiles/CU
    int b = g >> 4, h = g & 15;
    int t = threadIdx.x, w = t >> 6, l = t & 63, lg = l >> 4, lr = l & 15;
    const u16* base = qkv + (size_t)b * S_ * T3_;
    const u16* vbase = Vt + (size_t)g * 64 * S_;
    int prow = w * 16 + lr;          // local P row (wave-private slab, 0..127)
    int qb = qt * 128;
    int qrow = qb + w * 16 + lr;     // this lane's q (column of S^T)

    // staging: 512 threads cover one 64x64 tile in ONE pass
    int srow = w * 8 + (l >> 3);
    auto stage = [&](int kt2, int bs) {
        int kb2 = kt2 * 64;
        int ckg = (l & 7) ^ (srow & 7);          // pre-swizzled global chunk
        gload_lds16(base + (size_t)(kb2 + srow) * T3_ + NX_ + h * 64 + ckg * 8,
                    &k_lds[bs][w * 512]);
        gload_lds16(vbase + (size_t)srow * S_ + kb2 + ckg * 8,
                    &v_lds[bs][w * 512]);
    };

    f32x4 zero4 = {0.f, 0.f, 0.f, 0.f};

    bf16x8 qf[2];
#pragma unroll
    for (int ks = 0; ks < 2; ++ks)
        qf[ks] = *reinterpret_cast<const bf16x8*>(
            base + (size_t)qrow * T3_ + h * 64 + ks * 32 + lg * 8);

    f32x4 oacc[4];
#pragma unroll
    for (int dc = 0; dc < 4; ++dc) oacc[dc] = zero4;
    float mrun = -1e30f, lrun = 0.f;
    int nkt = 2 * qt + 2;            // block-uniform kv range
    int tw = 2 * qt + (w >> 2);      // this wave's last needed kv-tile

    stage(0, 0);
    __syncthreads();

    for (int kt = 0; kt < nkt; ++kt) {
        int cur = kt & 1;
        if (kt + 1 < nkt) stage(kt + 1, cur ^ 1);   // issue early; drains at end barrier

        if (kt <= tw) {
            int kb = kt * 64;
            // S^T = K Q^T : lane holds S[k = kb+kn*16+lg*4+r][q = qrow] (log2 units)
            f32x4 sacc[4];
#pragma unroll
            for (int kn = 0; kn < 4; ++kn) sacc[kn] = zero4;
            __builtin_amdgcn_s_setprio(1);
#pragma unroll
            for (int ks = 0; ks < 2; ++ks) {
#pragma unroll
                for (int kn = 0; kn < 4; ++kn) {
                    bf16x8 kf = *reinterpret_cast<const bf16x8*>(
                        &k_lds[cur][(kn * 16 + lr) * 64 + (((ks * 4 + lg) ^ (lr & 7)) * 8)]);
                    sacc[kn] = __builtin_amdgcn_mfma_f32_16x16x32_bf16(
                        kf, qf[ks], sacc[kn], 0, 0, 0);
                }
            }
            __builtin_amdgcn_s_setprio(0);

            if (kt == tw) {   // diagonal tile: causal mask (kv > q)
#pragma unroll
                for (int kn = 0; kn < 4; ++kn)
#pragma unroll
                    for (int r = 0; r < 4; ++r)
                        if (kb + kn * 16 + lg * 4 + r > qrow) sacc[kn][r] = -1e30f;
            }

            // in-register online softmax (log2 domain)
            float mx = -1e30f;
#pragma unroll
            for (int kn = 0; kn < 4; ++kn) {
                float a0 = fmaxf(sacc[kn][0], sacc[kn][1]);
                float a1 = fmaxf(sacc[kn][2], sacc[kn][3]);
                mx = fmaxf(mx, fmaxf(a0, a1));
            }
            mx = fmaxf(mx, __shfl_xor(mx, 16));
            mx = fmaxf(mx, __shfl_xor(mx, 32));

            bool noresc = __all(mx <= mrun + 1.5f);   // defer-max: P <= 2^1.5 = 2.83
            float mnew = noresc ? mrun : fmaxf(mrun, mx);

            float rs = 0.f;
#pragma unroll
            for (int kn = 0; kn < 4; ++kn)
#pragma unroll
                for (int r = 0; r < 4; ++r) {
                    float pv = exp2f(sacc[kn][r] - mnew);
                    sacc[kn][r] = pv;
                    rs += pv;
                }
            rs += __shfl_xor(rs, 16);
            rs += __shfl_xor(rs, 32);

            if (noresc) {
                lrun += rs;
            } else {
                float fsc = exp2f(mrun - mnew);
                mrun = mnew;
                lrun = lrun * fsc + rs;
                float f0 = __shfl(fsc, lg * 4 + 0);
                float f1 = __shfl(fsc, lg * 4 + 1);
                float f2 = __shfl(fsc, lg * 4 + 2);
                float f3 = __shfl(fsc, lg * 4 + 3);
#pragma unroll
                for (int dc = 0; dc < 4; ++dc) {
                    oacc[dc][0] *= f0; oacc[dc][1] *= f1;
                    oacc[dc][2] *= f2; oacc[dc][3] *= f3;
                }
            }

            // P -> LDS, packed 8B writes, swizzled (wave-private slab: no barrier needed)
#pragma unroll
            for (int kn = 0; kn < 4; ++kn) {
                bf16x4 pb;
                pb[0] = (__bf16)sacc[kn][0]; pb[1] = (__bf16)sacc[kn][1];
                pb[2] = (__bf16)sacc[kn][2]; pb[3] = (__bf16)sacc[kn][3];
                int byteoff = prow * 128 + (((2 * kn + (lg >> 1)) ^ (prow & 7)) * 16) + (lg & 1) * 8;
                *reinterpret_cast<bf16x4*>(reinterpret_cast<char*>(p_lds) + byteoff) = pb;
            }

            // O += P V  (A = P rows from LDS, B = Vt rows)
            __builtin_amdgcn_s_setprio(1);
#pragma unroll
            for (int ks = 0; ks < 2; ++ks) {
                bf16x8 pf = *reinterpret_cast<const bf16x8*>(
                    reinterpret_cast<char*>(p_lds) + prow * 128 + (((ks * 4 + lg) ^ (prow & 7)) * 16));
#pragma unroll
                for (int dc = 0; dc < 4; ++dc) {
                    bf16x8 vf = *reinterpret_cast<const bf16x8*>(
                        &v_lds[cur][(dc * 16 + lr) * 64 + (((ks * 4 + lg) ^ (lr & 7)) * 8)]);
                    oacc[dc] = __builtin_amdgcn_mfma_f32_16x16x32_bf16(
                        pf, vf, oacc[dc], 0, 0, 0);
                }
            }
            __builtin_amdgcn_s_setprio(0);
        }
        __syncthreads();   // single barrier/tile: k/v_lds[cur] reads done before restage
    }

    // epilogue: O /= l ; store bf16 [token][h*64+d]
    float inv = 1.f / lrun;
    float i0 = __shfl(inv, lg * 4 + 0);
    float i1 = __shfl(inv, lg * 4 + 1);
    float i2 = __shfl(inv, lg * 4 + 2);
    float i3 = __shfl(inv, lg * 4 + 3);
    u16* ob = outa + (size_t)b * S_ * NX_;
#pragma unroll
    for (int r = 0; r < 4; ++r) {
        float ir = (r == 0) ? i0 : (r == 1) ? i1 : (r == 2) ? i2 : i3;
        int row = qb + w * 16 + lg * 4 + r;
#pragma unroll
        for (int dc = 0; dc < 4; ++dc)
            ob[(size_t)row * NX_ + h * 64 + dc * 16 + lr] = bfbits(oacc[dc][r] * ir);
    }
}

extern "C" void kernel_launch(void* const* d_in, const int* in_sizes, int n_in,
                              void* d_out, int out_size, void* d_ws, size_t ws_size,
                              hipStream_t stream) {
    const float* x        = (const float*)d_in[0];
    const float* c_attn_w = (const float*)d_in[1];
    const float* c_attn_b = (const float*)d_in[2];
    const float* c_proj_w = (const float*)d_in[3];
    const float* c_proj_b = (const float*)d_in[4];
    float* out = (float*)d_out;

    u16* xb     = (u16*)d_ws;                         // [4096][1024] bf16  (8 MB)
    u16* wqkvT  = xb + (size_t)M_ * NX_;              // [3072][1024] bf16  (6 MB)
    u16* wprojT = wqkvT + (size_t)T3_ * NX_;          // [1024][1024] bf16  (2 MB)
    u16* qkv    = wprojT + (size_t)NX_ * NX_;         // [4096][3072] bf16  (24 MB; V part unused)
    u16* attno  = xb;                                 // reuse xb after GEMM1 (8 MB)
    u16* Vtp    = (u16*)d_out;                        // scratch: Vt 8 MB inside 16 MB out;
                                                      // fully overwritten by GEMM2 at the end

    // 1) fused prep: x -> bf16, both weights -> transposed bf16 (one launch)
    prep_kernel<<<8192, 256, 0, stream>>>(x, xb, c_attn_w, wqkvT, c_proj_w, wprojT);
    // 2) qkv = x @ c_attn_w + b (bf16, Q pre-scaled); V-part -> Vtp transposed
    gemm_bt_kernel<<<(M_ / BM) * (T3_ / BN), 256, 0, stream>>>(
        xb, wqkvT, c_attn_b, qkv, nullptr, Vtp, 2 * NX_, NX_, M_, T3_, NX_);
    // 3) attention (8-wave blocks, q-tile 128, 512 blocks)
    attn_kernel<<<512, 512, 0, stream>>>(qkv, Vtp, attno);
    // 4) out = attn @ c_proj_w + b  (f32 out)
    gemm_bt_kernel<<<(M_ / BM) * (NX_ / BN), 256, 0, stream>>>(
        attno, wprojT, c_proj_b, nullptr, out, nullptr, 0, 0, M_, NX_, NX_);
}

// Round 16
// 109.391 us; speedup vs baseline: 1.1328x; 1.0526x over previous
//
#include <hip/hip_runtime.h>
#include <cstdint>

typedef unsigned short u16;
typedef unsigned int u32;
typedef float f32x4 __attribute__((ext_vector_type(4)));
typedef __bf16 bf16x8 __attribute__((ext_vector_type(8)));
typedef __bf16 bf16x4 __attribute__((ext_vector_type(4)));
typedef u16 u16x8 __attribute__((ext_vector_type(8)));

#define B_ 2
#define S_ 2048
#define NX_ 1024
#define NH_ 16
#define HD_ 64
#define T3_ 3072
#define M_ 4096          // B_*S_ tokens
#define SCL 0.18033688011112042f   // 0.125 * log2(e); folded into Q at GEMM1 epilogue

__device__ __forceinline__ u16 bfbits(float f) {
    __bf16 h = (__bf16)f;            // native cvt (RNE), pairs to v_cvt_pk_bf16_f32
    return __builtin_bit_cast(u16, h);
}

__device__ __forceinline__ void gload_lds16(const void* g, void* l) {
    auto gp = reinterpret_cast<const __attribute__((address_space(1))) u32*>(
        reinterpret_cast<uintptr_t>(g));
    auto lp = reinterpret_cast<__attribute__((address_space(3))) u32*>(
        reinterpret_cast<uintptr_t>(l));
    __builtin_amdgcn_global_load_lds(gp, lp, 16, 0, 0);
}

// ---------------- fused prep: x->bf16 + both weight transposes, one launch ----------------
__global__ __launch_bounds__(256) void prep_kernel(const float* __restrict__ x,
                                                   u16* __restrict__ xb,
                                                   const float* __restrict__ w1,
                                                   u16* __restrict__ w1t,
                                                   const float* __restrict__ w2,
                                                   u16* __restrict__ w2t) {
    __shared__ float tile[32][33];
    int bid = blockIdx.x;
    if (bid < 4096) {                 // vectorized f32 -> bf16 convert of x
        int i = (bid * 256 + threadIdx.x) * 4;
        float4 v = *reinterpret_cast<const float4*>(x + i);
        bf16x4 o;
        o[0] = (__bf16)v.x; o[1] = (__bf16)v.y; o[2] = (__bf16)v.z; o[3] = (__bf16)v.w;
        *reinterpret_cast<bf16x4*>(xb + i) = o;
        return;
    }
    const float* W; u16* WT; int N, lb;
    if (bid < 4096 + 3072) { W = w1; WT = w1t; N = T3_; lb = bid - 4096; }
    else                   { W = w2; WT = w2t; N = NX_; lb = bid - 7168; }
    const int K = NX_;
    int nbx = N >> 5;
    int nb = (lb % nbx) << 5;
    int kb = (lb / nbx) << 5;
    int tx = threadIdx.x & 31, ty = threadIdx.x >> 5;
#pragma unroll
    for (int i = 0; i < 32; i += 8)
        tile[ty + i][tx] = W[(size_t)(kb + ty + i) * N + nb + tx];
    __syncthreads();
#pragma unroll
    for (int i = 0; i < 32; i += 8)
        WT[(size_t)(nb + ty + i) * K + kb + tx] = bfbits(tile[tx][ty + i]);
}

// ---------------- 128^2 bf16 GEMM, double-buffered prefetch + chunk-XOR swizzle ----------------
#define BM 128
#define BN 128
#define BK 64
__global__ __launch_bounds__(256) void gemm_bt_kernel(const u16* __restrict__ A,
                                                      const u16* __restrict__ Bt,
                                                      const float* __restrict__ bias,
                                                      u16* __restrict__ Cb,
                                                      float* __restrict__ Cf,
                                                      u16* __restrict__ Vt,
                                                      int vcol0, int qcols,
                                                      int M, int N, int K) {
    __shared__ u16 a_lds[2][BM * BK];
    __shared__ u16 b_lds[2][BN * BK];
    int nbn = N / BN;
    int nwg = gridDim.x;
    int orig = blockIdx.x;
    int wg = (orig & 7) * (nwg >> 3) + (orig >> 3);   // XCD-contiguous chunks
    int bm = wg / nbn, bn = wg % nbn;
    int t = threadIdx.x;
    int w = t >> 6, l = t & 63, lg = l >> 4, lr = l & 15;
    int wr = w >> 1, wc = w & 1;
    const u16* Abase = A + (size_t)bm * BM * K;
    const u16* Bbase = Bt + (size_t)bn * BN * K;

    f32x4 zero4 = {0.f, 0.f, 0.f, 0.f};
    f32x4 acc[4][4];
#pragma unroll
    for (int m = 0; m < 4; ++m)
#pragma unroll
        for (int n = 0; n < 4; ++n) acc[m][n] = zero4;

    auto stage = [&](int kt, int bs) {
#pragma unroll
        for (int it = 0; it < 4; ++it) {
            int idx = it * 256 + t;              // 0..1023 = 128 rows x 8 chunks
            int row = idx >> 3, ck = idx & 7;
            int cds = ck ^ (row & 7);            // data chunk stored in this slot
            int ubase = (it * 256 + w * 64) * 8; // u16 units, wave-uniform
            gload_lds16(Abase + (size_t)row * K + kt * BK + cds * 8, &a_lds[bs][ubase]);
            gload_lds16(Bbase + (size_t)row * K + kt * BK + cds * 8, &b_lds[bs][ubase]);
        }
    };

    stage(0, 0);
    __syncthreads();

    int nkt = K / BK;
    for (int kt = 0; kt < nkt; ++kt) {
        int cur = kt & 1;
        if (kt + 1 < nkt) stage(kt + 1, cur ^ 1);   // prefetch into other buffer

#pragma unroll
        for (int ks = 0; ks < 2; ++ks) {
            int ck = (ks * 4 + lg) ^ (lr & 7);      // row&7 == lr&7 for all fragment rows
            bf16x8 af[4], bf[4];
#pragma unroll
            for (int m = 0; m < 4; ++m)
                af[m] = *reinterpret_cast<const bf16x8*>(
                    &a_lds[cur][(wr * 64 + m * 16 + lr) * BK + ck * 8]);
#pragma unroll
            for (int n = 0; n < 4; ++n)
                bf[n] = *reinterpret_cast<const bf16x8*>(
                    &b_lds[cur][(wc * 64 + n * 16 + lr) * BK + ck * 8]);
            __builtin_amdgcn_s_setprio(1);
#pragma unroll
            for (int m = 0; m < 4; ++m)
#pragma unroll
                for (int n = 0; n < 4; ++n)
                    acc[m][n] = __builtin_amdgcn_mfma_f32_16x16x32_bf16(
                        af[m], bf[n], acc[m][n], 0, 0, 0);
            __builtin_amdgcn_s_setprio(0);
        }
        __syncthreads();   // one barrier/tile: drains prefetch (amortized)
    }

#pragma unroll
    for (int n = 0; n < 4; ++n) {
        int col0 = bn * BN + wc * 64 + n * 16;
        int col = col0 + lr;
        float bv = bias[col];
        float sc = (col0 < qcols) ? SCL : 1.0f;   // pre-scale Q columns
        bool isv = (Vt != nullptr) && (col0 >= vcol0);
#pragma unroll
        for (int m = 0; m < 4; ++m) {
            int row0 = bm * BM + wr * 64 + m * 16 + lg * 4;
            if (isv) {
                int nv = col - vcol0, hh = nv >> 6, dd = nv & 63;
                int bb = row0 >> 11, ss = row0 & 2047;
                bf16x4 pk;
#pragma unroll
                for (int r = 0; r < 4; ++r) pk[r] = (__bf16)(acc[m][n][r] + bv);
                *reinterpret_cast<bf16x4*>(
                    Vt + (((size_t)(bb * 16 + hh) * 64 + dd) << 11) + ss) = pk;
            } else {
#pragma unroll
                for (int r = 0; r < 4; ++r) {
                    float v = (acc[m][n][r] + bv) * sc;
                    if (Cf) Cf[(size_t)(row0 + r) * N + col] = v;
                    else    Cb[(size_t)(row0 + r) * N + col] = bfbits(v);
                }
            }
        }
    }
}

// ---------------- flash attention: 8-wave blocks, q-tile 128, KVBLK=128 ----------------
// 512 blocks x 512 thr. KVBLK=128 halves barriers/stage-rounds/softmax fixed costs
// per kv-element vs KVBLK=64 (LDS 80KB is free: grid caps residency at 2 blocks/CU).
// Diagonal tile computed fully with per-element masks (exp2(-inf)=0 -> P=0).
// P slab [128][64] reused in two wave-private half-passes per tile.
__global__ __launch_bounds__(512) void attn_kernel(const u16* __restrict__ qkv,
                                                   const u16* __restrict__ Vt,
                                                   u16* __restrict__ outa) {
    __shared__ u16 k_lds[2][8192];   // [kv 128][d 64], chunk16-swizzled ^ (row&7)
    __shared__ u16 v_lds[2][8192];   // [d 64][kv 128], chunk16-swizzled ^ (row&7)
    __shared__ u16 p_lds[8192];      // [q 128][kv 64] half-slab, reused 2x per tile

    int bid = blockIdx.x;
    int g = bid & 31;                // same g -> same XCD (stride 32 ≡ 0 mod 8)
    int j = bid >> 5;                // 0..15
    int qt = (j < 8) ? (15 - j) : (j - 8);   // CU pairs (15-k, k): uniform work/CU
    int b = g >> 4, h = g & 15;
    int t = threadIdx.x, w = t >> 6, l = t & 63, lg = l >> 4, lr = l & 15;
    const u16* base = qkv + (size_t)b * S_ * T3_;
    const u16* vbase = Vt + (size_t)g * 64 * S_;
    int prow = w * 16 + lr;          // local P row (wave-private slab, 0..127)
    int qb = qt * 128;
    int qrow = qb + w * 16 + lr;     // this lane's q (column of S^T)

    // staging: 512 threads x 2 passes cover one 128x64 K tile + 64x128 V tile
    auto stage = [&](int kt2, int bs) {
        int kb2 = kt2 * 128;
#pragma unroll
        for (int p = 0; p < 2; ++p) {
            int slot = w * 128 + p * 64 + l;     // 0..1023
            int ubase = (w * 128 + p * 64) * 8;  // u16 units, wave-uniform
            int rowK = slot >> 3, ckK = (slot & 7) ^ (rowK & 7);
            gload_lds16(base + (size_t)(kb2 + rowK) * T3_ + NX_ + h * 64 + ckK * 8,
                        &k_lds[bs][ubase]);
            int rowV = slot >> 4, ckV = (slot & 15) ^ (rowV & 7);
            gload_lds16(vbase + (size_t)rowV * S_ + kb2 + ckV * 8,
                        &v_lds[bs][ubase]);
        }
    };

    f32x4 zero4 = {0.f, 0.f, 0.f, 0.f};

    bf16x8 qf[2];
#pragma unroll
    for (int ks = 0; ks < 2; ++ks)
        qf[ks] = *reinterpret_cast<const bf16x8*>(
            base + (size_t)qrow * T3_ + h * 64 + ks * 32 + lg * 8);

    f32x4 oacc[4];
#pragma unroll
    for (int dc = 0; dc < 4; ++dc) oacc[dc] = zero4;
    float mrun = -1e30f, lrun = 0.f;
    int nkt = qt + 1;                // 128-wide kv tiles

    stage(0, 0);
    __syncthreads();

    for (int kt = 0; kt < nkt; ++kt) {
        int cur = kt & 1;
        if (kt + 1 < nkt) stage(kt + 1, cur ^ 1);   // issue early; drains at end barrier

        int kb = kt * 128;
        // S^T = K Q^T : lane holds S[k = kb+kn*16+lg*4+r][q = qrow] (log2 units)
        f32x4 sacc[8];
#pragma unroll
        for (int kn = 0; kn < 8; ++kn) sacc[kn] = zero4;
        __builtin_amdgcn_s_setprio(1);
#pragma unroll
        for (int ks = 0; ks < 2; ++ks) {
#pragma unroll
            for (int kn = 0; kn < 8; ++kn) {
                bf16x8 kf = *reinterpret_cast<const bf16x8*>(
                    &k_lds[cur][(kn * 16 + lr) * 64 + (((ks * 4 + lg) ^ (lr & 7)) * 8)]);
                sacc[kn] = __builtin_amdgcn_mfma_f32_16x16x32_bf16(
                    kf, qf[ks], sacc[kn], 0, 0, 0);
            }
        }
        __builtin_amdgcn_s_setprio(0);

        if (kt == qt) {   // diagonal tile: causal mask (kv > q), per element
#pragma unroll
            for (int kn = 0; kn < 8; ++kn)
#pragma unroll
                for (int r = 0; r < 4; ++r)
                    if (kb + kn * 16 + lg * 4 + r > qrow) sacc[kn][r] = -1e30f;
        }

        // in-register online softmax over 128 kv (log2 domain)
        float mx = -1e30f;
#pragma unroll
        for (int kn = 0; kn < 8; ++kn) {
            float a0 = fmaxf(sacc[kn][0], sacc[kn][1]);
            float a1 = fmaxf(sacc[kn][2], sacc[kn][3]);
            mx = fmaxf(mx, fmaxf(a0, a1));
        }
        mx = fmaxf(mx, __shfl_xor(mx, 16));
        mx = fmaxf(mx, __shfl_xor(mx, 32));

        bool noresc = __all(mx <= mrun + 1.5f);   // defer-max: P <= 2^1.5 = 2.83
        float mnew = noresc ? mrun : fmaxf(mrun, mx);

        float rs = 0.f;
#pragma unroll
        for (int kn = 0; kn < 8; ++kn)
#pragma unroll
            for (int r = 0; r < 4; ++r) {
                float pv = exp2f(sacc[kn][r] - mnew);
                sacc[kn][r] = pv;
                rs += pv;
            }
        rs += __shfl_xor(rs, 16);
        rs += __shfl_xor(rs, 32);

        if (noresc) {
            lrun += rs;
        } else {
            float fsc = exp2f(mrun - mnew);
            mrun = mnew;
            lrun = lrun * fsc + rs;
            float f0 = __shfl(fsc, lg * 4 + 0);
            float f1 = __shfl(fsc, lg * 4 + 1);
            float f2 = __shfl(fsc, lg * 4 + 2);
            float f3 = __shfl(fsc, lg * 4 + 3);
#pragma unroll
            for (int dc = 0; dc < 4; ++dc) {
                oacc[dc][0] *= f0; oacc[dc][1] *= f1;
                oacc[dc][2] *= f2; oacc[dc][3] *= f3;
            }
        }

        // PV in two 64-kv half-passes through the wave-private P slab
#pragma unroll
        for (int half = 0; half < 2; ++half) {
#pragma unroll
            for (int kn2 = 0; kn2 < 4; ++kn2) {
                int kn = half * 4 + kn2;
                bf16x4 pb;
                pb[0] = (__bf16)sacc[kn][0]; pb[1] = (__bf16)sacc[kn][1];
                pb[2] = (__bf16)sacc[kn][2]; pb[3] = (__bf16)sacc[kn][3];
                int byteoff = prow * 128 + (((2 * kn2 + (lg >> 1)) ^ (prow & 7)) * 16) + (lg & 1) * 8;
                *reinterpret_cast<bf16x4*>(reinterpret_cast<char*>(p_lds) + byteoff) = pb;
            }
            __builtin_amdgcn_s_setprio(1);
#pragma unroll
            for (int ks2 = 0; ks2 < 2; ++ks2) {
                bf16x8 pf = *reinterpret_cast<const bf16x8*>(
                    reinterpret_cast<char*>(p_lds) + prow * 128 + (((ks2 * 4 + lg) ^ (prow & 7)) * 16));
#pragma unroll
                for (int dc = 0; dc < 4; ++dc) {
                    bf16x8 vf = *reinterpret_cast<const bf16x8*>(
                        &v_lds[cur][(dc * 16 + lr) * 128 +
                                    (((half * 8 + ks2 * 4 + lg) ^ (lr & 7)) * 8)]);
                    oacc[dc] = __builtin_amdgcn_mfma_f32_16x16x32_bf16(
                        pf, vf, oacc[dc], 0, 0, 0);
                }
            }
            __builtin_amdgcn_s_setprio(0);
        }
        __syncthreads();   // single barrier/tile: k/v_lds[cur] reads done before restage
    }

    // epilogue: O /= l ; store bf16 [token][h*64+d]
    float inv = 1.f / lrun;
    float i0 = __shfl(inv, lg * 4 + 0);
    float i1 = __shfl(inv, lg * 4 + 1);
    float i2 = __shfl(inv, lg * 4 + 2);
    float i3 = __shfl(inv, lg * 4 + 3);
    u16* ob = outa + (size_t)b * S_ * NX_;
#pragma unroll
    for (int r = 0; r < 4; ++r) {
        float ir = (r == 0) ? i0 : (r == 1) ? i1 : (r == 2) ? i2 : i3;
        int row = qb + w * 16 + lg * 4 + r;
#pragma unroll
        for (int dc = 0; dc < 4; ++dc)
            ob[(size_t)row * NX_ + h * 64 + dc * 16 + lr] = bfbits(oacc[dc][r] * ir);
    }
}

extern "C" void kernel_launch(void* const* d_in, const int* in_sizes, int n_in,
                              void* d_out, int out_size, void* d_ws, size_t ws_size,
                              hipStream_t stream) {
    const float* x        = (const float*)d_in[0];
    const float* c_attn_w = (const float*)d_in[1];
    const float* c_attn_b = (const float*)d_in[2];
    const float* c_proj_w = (const float*)d_in[3];
    const float* c_proj_b = (const float*)d_in[4];
    float* out = (float*)d_out;

    u16* xb     = (u16*)d_ws;                         // [4096][1024] bf16  (8 MB)
    u16* wqkvT  = xb + (size_t)M_ * NX_;              // [3072][1024] bf16  (6 MB)
    u16* wprojT = wqkvT + (size_t)T3_ * NX_;          // [1024][1024] bf16  (2 MB)
    u16* qkv    = wprojT + (size_t)NX_ * NX_;         // [4096][3072] bf16  (24 MB; V part unused)
    u16* attno  = xb;                                 // reuse xb after GEMM1 (8 MB)
    u16* Vtp    = (u16*)d_out;                        // scratch: Vt 8 MB inside 16 MB out;
                                                      // fully overwritten by GEMM2 at the end

    // 1) fused prep: x -> bf16, both weights -> transposed bf16 (one launch)
    prep_kernel<<<8192, 256, 0, stream>>>(x, xb, c_attn_w, wqkvT, c_proj_w, wprojT);
    // 2) qkv = x @ c_attn_w + b (bf16, Q pre-scaled); V-part -> Vtp transposed
    gemm_bt_kernel<<<(M_ / BM) * (T3_ / BN), 256, 0, stream>>>(
        xb, wqkvT, c_attn_b, qkv, nullptr, Vtp, 2 * NX_, NX_, M_, T3_, NX_);
    // 3) attention (8-wave blocks, q-tile 128, KVBLK 128, 512 blocks)
    attn_kernel<<<512, 512, 0, stream>>>(qkv, Vtp, attno);
    // 4) out = attn @ c_proj_w + b  (f32 out)
    gemm_bt_kernel<<<(M_ / BM) * (NX_ / BN), 256, 0, stream>>>(
        attno, wprojT, c_proj_b, nullptr, out, nullptr, 0, 0, M_, NX_, NX_);
}

// Round 17
// 106.715 us; speedup vs baseline: 1.1612x; 1.0251x over previous
//
#include <hip/hip_runtime.h>
#include <cstdint>

typedef unsigned short u16;
typedef unsigned int u32;
typedef float f32x4 __attribute__((ext_vector_type(4)));
typedef __bf16 bf16x8 __attribute__((ext_vector_type(8)));
typedef __bf16 bf16x4 __attribute__((ext_vector_type(4)));
typedef u16 u16x8 __attribute__((ext_vector_type(8)));

#define B_ 2
#define S_ 2048
#define NX_ 1024
#define NH_ 16
#define HD_ 64
#define T3_ 3072
#define M_ 4096          // B_*S_ tokens
#define SCL 0.18033688011112042f   // 0.125 * log2(e); folded into Q at GEMM1 epilogue

__device__ __forceinline__ u16 bfbits(float f) {
    __bf16 h = (__bf16)f;            // native cvt (RNE), pairs to v_cvt_pk_bf16_f32
    return __builtin_bit_cast(u16, h);
}

__device__ __forceinline__ void gload_lds16(const void* g, void* l) {
    auto gp = reinterpret_cast<const __attribute__((address_space(1))) u32*>(
        reinterpret_cast<uintptr_t>(g));
    auto lp = reinterpret_cast<__attribute__((address_space(3))) u32*>(
        reinterpret_cast<uintptr_t>(l));
    __builtin_amdgcn_global_load_lds(gp, lp, 16, 0, 0);
}

// ---------------- fused prep: x->bf16 + both weight transposes, one launch ----------------
__global__ __launch_bounds__(256) void prep_kernel(const float* __restrict__ x,
                                                   u16* __restrict__ xb,
                                                   const float* __restrict__ w1,
                                                   u16* __restrict__ w1t,
                                                   const float* __restrict__ w2,
                                                   u16* __restrict__ w2t) {
    __shared__ float tile[32][33];
    int bid = blockIdx.x;
    if (bid < 4096) {                 // vectorized f32 -> bf16 convert of x
        int i = (bid * 256 + threadIdx.x) * 4;
        float4 v = *reinterpret_cast<const float4*>(x + i);
        bf16x4 o;
        o[0] = (__bf16)v.x; o[1] = (__bf16)v.y; o[2] = (__bf16)v.z; o[3] = (__bf16)v.w;
        *reinterpret_cast<bf16x4*>(xb + i) = o;
        return;
    }
    const float* W; u16* WT; int N, lb;
    if (bid < 4096 + 3072) { W = w1; WT = w1t; N = T3_; lb = bid - 4096; }
    else                   { W = w2; WT = w2t; N = NX_; lb = bid - 7168; }
    const int K = NX_;
    int nbx = N >> 5;
    int nb = (lb % nbx) << 5;
    int kb = (lb / nbx) << 5;
    int tx = threadIdx.x & 31, ty = threadIdx.x >> 5;
#pragma unroll
    for (int i = 0; i < 32; i += 8)
        tile[ty + i][tx] = W[(size_t)(kb + ty + i) * N + nb + tx];
    __syncthreads();
#pragma unroll
    for (int i = 0; i < 32; i += 8)
        WT[(size_t)(nb + ty + i) * K + kb + tx] = bfbits(tile[tx][ty + i]);
}

// ---------------- 128^2 bf16 GEMM, 8 waves, dbuf prefetch + chunk-XOR swizzle ----------------
// 512 thr (8 waves, 2Mx4N; wave tile 64x32). Same 64KB dbuf LDS -> 2 blocks/CU but
// 16 waves/CU (was 8): doubles latency-hiding for the per-tile barrier drain (m114).
// Columns < qcols scaled by SCL; columns >= vcol0 written transposed: Vt[g][d][s].
#define BM 128
#define BN 128
#define BK 64
__global__ __launch_bounds__(512) void gemm_bt_kernel(const u16* __restrict__ A,
                                                      const u16* __restrict__ Bt,
                                                      const float* __restrict__ bias,
                                                      u16* __restrict__ Cb,
                                                      float* __restrict__ Cf,
                                                      u16* __restrict__ Vt,
                                                      int vcol0, int qcols,
                                                      int M, int N, int K) {
    __shared__ u16 a_lds[2][BM * BK];
    __shared__ u16 b_lds[2][BN * BK];
    int nbn = N / BN;
    int nwg = gridDim.x;
    int orig = blockIdx.x;
    int wg = (orig & 7) * (nwg >> 3) + (orig >> 3);   // XCD-contiguous chunks
    int bm = wg / nbn, bn = wg % nbn;
    int t = threadIdx.x;
    int wid = t >> 6, l = t & 63, lg = l >> 4, lr = l & 15;
    int wr = wid >> 2, wc = wid & 3;                  // 2 x 4 wave grid
    const u16* Abase = A + (size_t)bm * BM * K;
    const u16* Bbase = Bt + (size_t)bn * BN * K;

    f32x4 zero4 = {0.f, 0.f, 0.f, 0.f};
    f32x4 acc[4][2];
#pragma unroll
    for (int m = 0; m < 4; ++m)
#pragma unroll
        for (int n = 0; n < 2; ++n) acc[m][n] = zero4;

    auto stage = [&](int kt, int bs) {
#pragma unroll
        for (int it = 0; it < 2; ++it) {
            int idx = it * 512 + t;               // 0..1023 = 128 rows x 8 chunks
            int row = idx >> 3, ck = idx & 7;
            int cds = ck ^ (row & 7);             // data chunk stored in this slot
            int ubase = (it * 512 + wid * 64) * 8; // u16 units, wave-uniform
            gload_lds16(Abase + (size_t)row * K + kt * BK + cds * 8, &a_lds[bs][ubase]);
            gload_lds16(Bbase + (size_t)row * K + kt * BK + cds * 8, &b_lds[bs][ubase]);
        }
    };

    stage(0, 0);
    __syncthreads();

    int nkt = K / BK;
    for (int kt = 0; kt < nkt; ++kt) {
        int cur = kt & 1;
        if (kt + 1 < nkt) stage(kt + 1, cur ^ 1);   // prefetch into other buffer

#pragma unroll
        for (int ks = 0; ks < 2; ++ks) {
            int ck = (ks * 4 + lg) ^ (lr & 7);      // row&7 == lr&7 for all fragment rows
            bf16x8 af[4], bf[2];
#pragma unroll
            for (int m = 0; m < 4; ++m)
                af[m] = *reinterpret_cast<const bf16x8*>(
                    &a_lds[cur][(wr * 64 + m * 16 + lr) * BK + ck * 8]);
#pragma unroll
            for (int n = 0; n < 2; ++n)
                bf[n] = *reinterpret_cast<const bf16x8*>(
                    &b_lds[cur][(wc * 32 + n * 16 + lr) * BK + ck * 8]);
            __builtin_amdgcn_s_setprio(1);
#pragma unroll
            for (int m = 0; m < 4; ++m)
#pragma unroll
                for (int n = 0; n < 2; ++n)
                    acc[m][n] = __builtin_amdgcn_mfma_f32_16x16x32_bf16(
                        af[m], bf[n], acc[m][n], 0, 0, 0);
            __builtin_amdgcn_s_setprio(0);
        }
        __syncthreads();   // one barrier/tile: drains prefetch (amortized)
    }

#pragma unroll
    for (int n = 0; n < 2; ++n) {
        int col0 = bn * BN + wc * 32 + n * 16;
        int col = col0 + lr;
        float bv = bias[col];
        float sc = (col0 < qcols) ? SCL : 1.0f;   // pre-scale Q columns
        bool isv = (Vt != nullptr) && (col0 >= vcol0);
#pragma unroll
        for (int m = 0; m < 4; ++m) {
            int row0 = bm * BM + wr * 64 + m * 16 + lg * 4;
            if (isv) {
                int nv = col - vcol0, hh = nv >> 6, dd = nv & 63;
                int bb = row0 >> 11, ss = row0 & 2047;
                bf16x4 pk;
#pragma unroll
                for (int r = 0; r < 4; ++r) pk[r] = (__bf16)(acc[m][n][r] + bv);
                *reinterpret_cast<bf16x4*>(
                    Vt + (((size_t)(bb * 16 + hh) * 64 + dd) << 11) + ss) = pk;
            } else {
#pragma unroll
                for (int r = 0; r < 4; ++r) {
                    float v = (acc[m][n][r] + bv) * sc;
                    if (Cf) Cf[(size_t)(row0 + r) * N + col] = v;
                    else    Cb[(size_t)(row0 + r) * N + col] = bfbits(v);
                }
            }
        }
    }
}

// ---------------- flash attention (R16 best): 8-wave blocks, q-tile 128, KVBLK=128 ----------------
__global__ __launch_bounds__(512) void attn_kernel(const u16* __restrict__ qkv,
                                                   const u16* __restrict__ Vt,
                                                   u16* __restrict__ outa) {
    __shared__ u16 k_lds[2][8192];   // [kv 128][d 64], chunk16-swizzled ^ (row&7)
    __shared__ u16 v_lds[2][8192];   // [d 64][kv 128], chunk16-swizzled ^ (row&7)
    __shared__ u16 p_lds[8192];      // [q 128][kv 64] half-slab, reused 2x per tile

    int bid = blockIdx.x;
    int g = bid & 31;                // same g -> same XCD (stride 32 ≡ 0 mod 8)
    int j = bid >> 5;                // 0..15
    int qt = (j < 8) ? (15 - j) : (j - 8);   // CU pairs (15-k, k): uniform work/CU
    int b = g >> 4, h = g & 15;
    int t = threadIdx.x, w = t >> 6, l = t & 63, lg = l >> 4, lr = l & 15;
    const u16* base = qkv + (size_t)b * S_ * T3_;
    const u16* vbase = Vt + (size_t)g * 64 * S_;
    int prow = w * 16 + lr;          // local P row (wave-private slab, 0..127)
    int qb = qt * 128;
    int qrow = qb + w * 16 + lr;     // this lane's q (column of S^T)

    // staging: 512 threads x 2 passes cover one 128x64 K tile + 64x128 V tile
    auto stage = [&](int kt2, int bs) {
        int kb2 = kt2 * 128;
#pragma unroll
        for (int p = 0; p < 2; ++p) {
            int slot = w * 128 + p * 64 + l;     // 0..1023
            int ubase = (w * 128 + p * 64) * 8;  // u16 units, wave-uniform
            int rowK = slot >> 3, ckK = (slot & 7) ^ (rowK & 7);
            gload_lds16(base + (size_t)(kb2 + rowK) * T3_ + NX_ + h * 64 + ckK * 8,
                        &k_lds[bs][ubase]);
            int rowV = slot >> 4, ckV = (slot & 15) ^ (rowV & 7);
            gload_lds16(vbase + (size_t)rowV * S_ + kb2 + ckV * 8,
                        &v_lds[bs][ubase]);
        }
    };

    f32x4 zero4 = {0.f, 0.f, 0.f, 0.f};

    bf16x8 qf[2];
#pragma unroll
    for (int ks = 0; ks < 2; ++ks)
        qf[ks] = *reinterpret_cast<const bf16x8*>(
            base + (size_t)qrow * T3_ + h * 64 + ks * 32 + lg * 8);

    f32x4 oacc[4];
#pragma unroll
    for (int dc = 0; dc < 4; ++dc) oacc[dc] = zero4;
    float mrun = -1e30f, lrun = 0.f;
    int nkt = qt + 1;                // 128-wide kv tiles

    stage(0, 0);
    __syncthreads();

    for (int kt = 0; kt < nkt; ++kt) {
        int cur = kt & 1;
        if (kt + 1 < nkt) stage(kt + 1, cur ^ 1);   // issue early; drains at end barrier

        int kb = kt * 128;
        // S^T = K Q^T : lane holds S[k = kb+kn*16+lg*4+r][q = qrow] (log2 units)
        f32x4 sacc[8];
#pragma unroll
        for (int kn = 0; kn < 8; ++kn) sacc[kn] = zero4;
        __builtin_amdgcn_s_setprio(1);
#pragma unroll
        for (int ks = 0; ks < 2; ++ks) {
#pragma unroll
            for (int kn = 0; kn < 8; ++kn) {
                bf16x8 kf = *reinterpret_cast<const bf16x8*>(
                    &k_lds[cur][(kn * 16 + lr) * 64 + (((ks * 4 + lg) ^ (lr & 7)) * 8)]);
                sacc[kn] = __builtin_amdgcn_mfma_f32_16x16x32_bf16(
                    kf, qf[ks], sacc[kn], 0, 0, 0);
            }
        }
        __builtin_amdgcn_s_setprio(0);

        if (kt == qt) {   // diagonal tile: causal mask (kv > q), per element
#pragma unroll
            for (int kn = 0; kn < 8; ++kn)
#pragma unroll
                for (int r = 0; r < 4; ++r)
                    if (kb + kn * 16 + lg * 4 + r > qrow) sacc[kn][r] = -1e30f;
        }

        // in-register online softmax over 128 kv (log2 domain)
        float mx = -1e30f;
#pragma unroll
        for (int kn = 0; kn < 8; ++kn) {
            float a0 = fmaxf(sacc[kn][0], sacc[kn][1]);
            float a1 = fmaxf(sacc[kn][2], sacc[kn][3]);
            mx = fmaxf(mx, fmaxf(a0, a1));
        }
        mx = fmaxf(mx, __shfl_xor(mx, 16));
        mx = fmaxf(mx, __shfl_xor(mx, 32));

        bool noresc = __all(mx <= mrun + 1.5f);   // defer-max: P <= 2^1.5 = 2.83
        float mnew = noresc ? mrun : fmaxf(mrun, mx);

        float rs = 0.f;
#pragma unroll
        for (int kn = 0; kn < 8; ++kn)
#pragma unroll
            for (int r = 0; r < 4; ++r) {
                float pv = exp2f(sacc[kn][r] - mnew);
                sacc[kn][r] = pv;
                rs += pv;
            }
        rs += __shfl_xor(rs, 16);
        rs += __shfl_xor(rs, 32);

        if (noresc) {
            lrun += rs;
        } else {
            float fsc = exp2f(mrun - mnew);
            mrun = mnew;
            lrun = lrun * fsc + rs;
            float f0 = __shfl(fsc, lg * 4 + 0);
            float f1 = __shfl(fsc, lg * 4 + 1);
            float f2 = __shfl(fsc, lg * 4 + 2);
            float f3 = __shfl(fsc, lg * 4 + 3);
#pragma unroll
            for (int dc = 0; dc < 4; ++dc) {
                oacc[dc][0] *= f0; oacc[dc][1] *= f1;
                oacc[dc][2] *= f2; oacc[dc][3] *= f3;
            }
        }

        // PV in two 64-kv half-passes through the wave-private P slab
#pragma unroll
        for (int half = 0; half < 2; ++half) {
#pragma unroll
            for (int kn2 = 0; kn2 < 4; ++kn2) {
                int kn = half * 4 + kn2;
                bf16x4 pb;
                pb[0] = (__bf16)sacc[kn][0]; pb[1] = (__bf16)sacc[kn][1];
                pb[2] = (__bf16)sacc[kn][2]; pb[3] = (__bf16)sacc[kn][3];
                int byteoff = prow * 128 + (((2 * kn2 + (lg >> 1)) ^ (prow & 7)) * 16) + (lg & 1) * 8;
                *reinterpret_cast<bf16x4*>(reinterpret_cast<char*>(p_lds) + byteoff) = pb;
            }
            __builtin_amdgcn_s_setprio(1);
#pragma unroll
            for (int ks2 = 0; ks2 < 2; ++ks2) {
                bf16x8 pf = *reinterpret_cast<const bf16x8*>(
                    reinterpret_cast<char*>(p_lds) + prow * 128 + (((ks2 * 4 + lg) ^ (prow & 7)) * 16));
#pragma unroll
                for (int dc = 0; dc < 4; ++dc) {
                    bf16x8 vf = *reinterpret_cast<const bf16x8*>(
                        &v_lds[cur][(dc * 16 + lr) * 128 +
                                    (((half * 8 + ks2 * 4 + lg) ^ (lr & 7)) * 8)]);
                    oacc[dc] = __builtin_amdgcn_mfma_f32_16x16x32_bf16(
                        pf, vf, oacc[dc], 0, 0, 0);
                }
            }
            __builtin_amdgcn_s_setprio(0);
        }
        __syncthreads();   // single barrier/tile: k/v_lds[cur] reads done before restage
    }

    // epilogue: O /= l ; store bf16 [token][h*64+d]
    float inv = 1.f / lrun;
    float i0 = __shfl(inv, lg * 4 + 0);
    float i1 = __shfl(inv, lg * 4 + 1);
    float i2 = __shfl(inv, lg * 4 + 2);
    float i3 = __shfl(inv, lg * 4 + 3);
    u16* ob = outa + (size_t)b * S_ * NX_;
#pragma unroll
    for (int r = 0; r < 4; ++r) {
        float ir = (r == 0) ? i0 : (r == 1) ? i1 : (r == 2) ? i2 : i3;
        int row = qb + w * 16 + lg * 4 + r;
#pragma unroll
        for (int dc = 0; dc < 4; ++dc)
            ob[(size_t)row * NX_ + h * 64 + dc * 16 + lr] = bfbits(oacc[dc][r] * ir);
    }
}

extern "C" void kernel_launch(void* const* d_in, const int* in_sizes, int n_in,
                              void* d_out, int out_size, void* d_ws, size_t ws_size,
                              hipStream_t stream) {
    const float* x        = (const float*)d_in[0];
    const float* c_attn_w = (const float*)d_in[1];
    const float* c_attn_b = (const float*)d_in[2];
    const float* c_proj_w = (const float*)d_in[3];
    const float* c_proj_b = (const float*)d_in[4];
    float* out = (float*)d_out;

    u16* xb     = (u16*)d_ws;                         // [4096][1024] bf16  (8 MB)
    u16* wqkvT  = xb + (size_t)M_ * NX_;              // [3072][1024] bf16  (6 MB)
    u16* wprojT = wqkvT + (size_t)T3_ * NX_;          // [1024][1024] bf16  (2 MB)
    u16* qkv    = wprojT + (size_t)NX_ * NX_;         // [4096][3072] bf16  (24 MB; V part unused)
    u16* attno  = xb;                                 // reuse xb after GEMM1 (8 MB)
    u16* Vtp    = (u16*)d_out;                        // scratch: Vt 8 MB inside 16 MB out;
                                                      // fully overwritten by GEMM2 at the end

    // 1) fused prep: x -> bf16, both weights -> transposed bf16 (one launch)
    prep_kernel<<<8192, 256, 0, stream>>>(x, xb, c_attn_w, wqkvT, c_proj_w, wprojT);
    // 2) qkv = x @ c_attn_w + b (bf16, Q pre-scaled, 8-wave GEMM); V-part -> Vtp
    gemm_bt_kernel<<<(M_ / BM) * (T3_ / BN), 512, 0, stream>>>(
        xb, wqkvT, c_attn_b, qkv, nullptr, Vtp, 2 * NX_, NX_, M_, T3_, NX_);
    // 3) attention (8-wave blocks, q-tile 128, KVBLK 128, 512 blocks)
    attn_kernel<<<512, 512, 0, stream>>>(qkv, Vtp, attno);
    // 4) out = attn @ c_proj_w + b  (f32 out, 8-wave GEMM)
    gemm_bt_kernel<<<(M_ / BM) * (NX_ / BN), 512, 0, stream>>>(
        attno, wprojT, c_proj_b, nullptr, out, nullptr, 0, 0, M_, NX_, NX_);
}

// Round 18
// 106.552 us; speedup vs baseline: 1.1630x; 1.0015x over previous
//
#include <hip/hip_runtime.h>
#include <cstdint>

typedef unsigned short u16;
typedef unsigned int u32;
typedef float f32x4 __attribute__((ext_vector_type(4)));
typedef __bf16 bf16x8 __attribute__((ext_vector_type(8)));
typedef __bf16 bf16x4 __attribute__((ext_vector_type(4)));
typedef u16 u16x8 __attribute__((ext_vector_type(8)));

#define B_ 2
#define S_ 2048
#define NX_ 1024
#define NH_ 16
#define HD_ 64
#define T3_ 3072
#define M_ 4096          // B_*S_ tokens
#define SCL 0.18033688011112042f   // 0.125 * log2(e); folded into Q at GEMM1 epilogue

__device__ __forceinline__ u16 bfbits(float f) {
    __bf16 h = (__bf16)f;            // native cvt (RNE), pairs to v_cvt_pk_bf16_f32
    return __builtin_bit_cast(u16, h);
}

__device__ __forceinline__ void gload_lds16(const void* g, void* l) {
    auto gp = reinterpret_cast<const __attribute__((address_space(1))) u32*>(
        reinterpret_cast<uintptr_t>(g));
    auto lp = reinterpret_cast<__attribute__((address_space(3))) u32*>(
        reinterpret_cast<uintptr_t>(l));
    __builtin_amdgcn_global_load_lds(gp, lp, 16, 0, 0);
}

// ---------------- fused prep: x->bf16 + both weight transposes, one launch ----------------
__global__ __launch_bounds__(256) void prep_kernel(const float* __restrict__ x,
                                                   u16* __restrict__ xb,
                                                   const float* __restrict__ w1,
                                                   u16* __restrict__ w1t,
                                                   const float* __restrict__ w2,
                                                   u16* __restrict__ w2t) {
    __shared__ float tile[32][33];
    int bid = blockIdx.x;
    if (bid < 4096) {                 // vectorized f32 -> bf16 convert of x
        int i = (bid * 256 + threadIdx.x) * 4;
        float4 v = *reinterpret_cast<const float4*>(x + i);
        bf16x4 o;
        o[0] = (__bf16)v.x; o[1] = (__bf16)v.y; o[2] = (__bf16)v.z; o[3] = (__bf16)v.w;
        *reinterpret_cast<bf16x4*>(xb + i) = o;
        return;
    }
    const float* W; u16* WT; int N, lb;
    if (bid < 4096 + 3072) { W = w1; WT = w1t; N = T3_; lb = bid - 4096; }
    else                   { W = w2; WT = w2t; N = NX_; lb = bid - 7168; }
    const int K = NX_;
    int nbx = N >> 5;
    int nb = (lb % nbx) << 5;
    int kb = (lb / nbx) << 5;
    int tx = threadIdx.x & 31, ty = threadIdx.x >> 5;
#pragma unroll
    for (int i = 0; i < 32; i += 8)
        tile[ty + i][tx] = W[(size_t)(kb + ty + i) * N + nb + tx];
    __syncthreads();
#pragma unroll
    for (int i = 0; i < 32; i += 8)
        WT[(size_t)(nb + ty + i) * K + kb + tx] = bfbits(tile[tx][ty + i]);
}

// ---------------- 128^2 bf16 GEMM, 8 waves, dbuf prefetch + chunk-XOR swizzle ----------------
// 512 thr (8 waves, 2Mx4N; wave tile 64x32). GEMM1 only (N=3072, grid 768:
// 512 resident + 256 backfill). Columns < qcols scaled by SCL; columns >= vcol0
// written transposed per-head: Vt[g][d][s].
#define BM 128
#define BN 128
#define BK 64
__global__ __launch_bounds__(512) void gemm_bt_kernel(const u16* __restrict__ A,
                                                      const u16* __restrict__ Bt,
                                                      const float* __restrict__ bias,
                                                      u16* __restrict__ Cb,
                                                      float* __restrict__ Cf,
                                                      u16* __restrict__ Vt,
                                                      int vcol0, int qcols,
                                                      int M, int N, int K) {
    __shared__ u16 a_lds[2][BM * BK];
    __shared__ u16 b_lds[2][BN * BK];
    int nbn = N / BN;
    int nwg = gridDim.x;
    int orig = blockIdx.x;
    int wg = (orig & 7) * (nwg >> 3) + (orig >> 3);   // XCD-contiguous chunks
    int bm = wg / nbn, bn = wg % nbn;
    int t = threadIdx.x;
    int wid = t >> 6, l = t & 63, lg = l >> 4, lr = l & 15;
    int wr = wid >> 2, wc = wid & 3;                  // 2 x 4 wave grid
    const u16* Abase = A + (size_t)bm * BM * K;
    const u16* Bbase = Bt + (size_t)bn * BN * K;

    f32x4 zero4 = {0.f, 0.f, 0.f, 0.f};
    f32x4 acc[4][2];
#pragma unroll
    for (int m = 0; m < 4; ++m)
#pragma unroll
        for (int n = 0; n < 2; ++n) acc[m][n] = zero4;

    auto stage = [&](int kt, int bs) {
#pragma unroll
        for (int it = 0; it < 2; ++it) {
            int idx = it * 512 + t;               // 0..1023 = 128 rows x 8 chunks
            int row = idx >> 3, ck = idx & 7;
            int cds = ck ^ (row & 7);             // data chunk stored in this slot
            int ubase = (it * 512 + wid * 64) * 8; // u16 units, wave-uniform
            gload_lds16(Abase + (size_t)row * K + kt * BK + cds * 8, &a_lds[bs][ubase]);
            gload_lds16(Bbase + (size_t)row * K + kt * BK + cds * 8, &b_lds[bs][ubase]);
        }
    };

    stage(0, 0);
    __syncthreads();

    int nkt = K / BK;
    for (int kt = 0; kt < nkt; ++kt) {
        int cur = kt & 1;
        if (kt + 1 < nkt) stage(kt + 1, cur ^ 1);   // prefetch into other buffer

#pragma unroll
        for (int ks = 0; ks < 2; ++ks) {
            int ck = (ks * 4 + lg) ^ (lr & 7);      // row&7 == lr&7 for all fragment rows
            bf16x8 af[4], bf[2];
#pragma unroll
            for (int m = 0; m < 4; ++m)
                af[m] = *reinterpret_cast<const bf16x8*>(
                    &a_lds[cur][(wr * 64 + m * 16 + lr) * BK + ck * 8]);
#pragma unroll
            for (int n = 0; n < 2; ++n)
                bf[n] = *reinterpret_cast<const bf16x8*>(
                    &b_lds[cur][(wc * 32 + n * 16 + lr) * BK + ck * 8]);
            __builtin_amdgcn_s_setprio(1);
#pragma unroll
            for (int m = 0; m < 4; ++m)
#pragma unroll
                for (int n = 0; n < 2; ++n)
                    acc[m][n] = __builtin_amdgcn_mfma_f32_16x16x32_bf16(
                        af[m], bf[n], acc[m][n], 0, 0, 0);
            __builtin_amdgcn_s_setprio(0);
        }
        __syncthreads();   // one barrier/tile: drains prefetch (amortized)
    }

#pragma unroll
    for (int n = 0; n < 2; ++n) {
        int col0 = bn * BN + wc * 32 + n * 16;
        int col = col0 + lr;
        float bv = bias[col];
        float sc = (col0 < qcols) ? SCL : 1.0f;   // pre-scale Q columns
        bool isv = (Vt != nullptr) && (col0 >= vcol0);
#pragma unroll
        for (int m = 0; m < 4; ++m) {
            int row0 = bm * BM + wr * 64 + m * 16 + lg * 4;
            if (isv) {
                int nv = col - vcol0, hh = nv >> 6, dd = nv & 63;
                int bb = row0 >> 11, ss = row0 & 2047;
                bf16x4 pk;
#pragma unroll
                for (int r = 0; r < 4; ++r) pk[r] = (__bf16)(acc[m][n][r] + bv);
                *reinterpret_cast<bf16x4*>(
                    Vt + (((size_t)(bb * 16 + hh) * 64 + dd) << 11) + ss) = pk;
            } else {
#pragma unroll
                for (int r = 0; r < 4; ++r) {
                    float v = (acc[m][n][r] + bv) * sc;
                    if (Cf) Cf[(size_t)(row0 + r) * N + col] = v;
                    else    Cb[(size_t)(row0 + r) * N + col] = bfbits(v);
                }
            }
        }
    }
}

// ---------------- 128x64 bf16 GEMM for GEMM2 (N=1024): grid 512 = 2 blocks/CU ----------------
// Fixes GEMM2's grid bug (BN=128 -> 256 blocks = 1/CU, latency-naked). 8 waves
// (4Mx2N; wave tile 32x32, acc[2][2]); LDS 48KB dbuf; same prefetch + swizzle.
__global__ __launch_bounds__(512) void gemm_bt64_kernel(const u16* __restrict__ A,
                                                        const u16* __restrict__ Bt,
                                                        const float* __restrict__ bias,
                                                        float* __restrict__ Cf,
                                                        int M, int N, int K) {
    __shared__ u16 a_lds[2][BM * BK];        // 128 x 64
    __shared__ u16 b_lds[2][64 * BK];        // 64 x 64
    int nbn = N / 64;
    int nwg = gridDim.x;
    int orig = blockIdx.x;
    int wg = (orig & 7) * (nwg >> 3) + (orig >> 3);   // XCD-contiguous chunks
    int bm = wg / nbn, bn = wg % nbn;
    int t = threadIdx.x;
    int wid = t >> 6, l = t & 63, lg = l >> 4, lr = l & 15;
    int wr = wid >> 1, wc = wid & 1;                  // 4 x 2 wave grid
    const u16* Abase = A + (size_t)bm * BM * K;
    const u16* Bbase = Bt + (size_t)bn * 64 * K;

    f32x4 zero4 = {0.f, 0.f, 0.f, 0.f};
    f32x4 acc[2][2];
#pragma unroll
    for (int m = 0; m < 2; ++m)
#pragma unroll
        for (int n = 0; n < 2; ++n) acc[m][n] = zero4;

    auto stage = [&](int kt, int bs) {
#pragma unroll
        for (int it = 0; it < 2; ++it) {     // A: 1024 chunks
            int idx = it * 512 + t;
            int row = idx >> 3, ck = idx & 7;
            int cds = ck ^ (row & 7);
            int ubase = (it * 512 + wid * 64) * 8;
            gload_lds16(Abase + (size_t)row * K + kt * BK + cds * 8, &a_lds[bs][ubase]);
        }
        {                                     // B: 512 chunks
            int row = t >> 3, ck = t & 7;
            int cds = ck ^ (row & 7);
            int ubase = (wid * 64) * 8;
            gload_lds16(Bbase + (size_t)row * K + kt * BK + cds * 8, &b_lds[bs][ubase]);
        }
    };

    stage(0, 0);
    __syncthreads();

    int nkt = K / BK;
    for (int kt = 0; kt < nkt; ++kt) {
        int cur = kt & 1;
        if (kt + 1 < nkt) stage(kt + 1, cur ^ 1);   // prefetch into other buffer

#pragma unroll
        for (int ks = 0; ks < 2; ++ks) {
            int ck = (ks * 4 + lg) ^ (lr & 7);
            bf16x8 af[2], bf[2];
#pragma unroll
            for (int m = 0; m < 2; ++m)
                af[m] = *reinterpret_cast<const bf16x8*>(
                    &a_lds[cur][(wr * 32 + m * 16 + lr) * BK + ck * 8]);
#pragma unroll
            for (int n = 0; n < 2; ++n)
                bf[n] = *reinterpret_cast<const bf16x8*>(
                    &b_lds[cur][(wc * 32 + n * 16 + lr) * BK + ck * 8]);
            __builtin_amdgcn_s_setprio(1);
#pragma unroll
            for (int m = 0; m < 2; ++m)
#pragma unroll
                for (int n = 0; n < 2; ++n)
                    acc[m][n] = __builtin_amdgcn_mfma_f32_16x16x32_bf16(
                        af[m], bf[n], acc[m][n], 0, 0, 0);
            __builtin_amdgcn_s_setprio(0);
        }
        __syncthreads();   // one barrier/tile
    }

#pragma unroll
    for (int n = 0; n < 2; ++n) {
        int col = bn * 64 + wc * 32 + n * 16 + lr;
        float bv = bias[col];
#pragma unroll
        for (int m = 0; m < 2; ++m) {
            int row0 = bm * BM + wr * 32 + m * 16 + lg * 4;
#pragma unroll
            for (int r = 0; r < 4; ++r)
                Cf[(size_t)(row0 + r) * N + col] = acc[m][n][r] + bv;
        }
    }
}

// ---------------- flash attention (R16/R17 best): 8-wave blocks, q-tile 128, KVBLK=128 ----------------
__global__ __launch_bounds__(512) void attn_kernel(const u16* __restrict__ qkv,
                                                   const u16* __restrict__ Vt,
                                                   u16* __restrict__ outa) {
    __shared__ u16 k_lds[2][8192];   // [kv 128][d 64], chunk16-swizzled ^ (row&7)
    __shared__ u16 v_lds[2][8192];   // [d 64][kv 128], chunk16-swizzled ^ (row&7)
    __shared__ u16 p_lds[8192];      // [q 128][kv 64] half-slab, reused 2x per tile

    int bid = blockIdx.x;
    int g = bid & 31;                // same g -> same XCD (stride 32 ≡ 0 mod 8)
    int j = bid >> 5;                // 0..15
    int qt = (j < 8) ? (15 - j) : (j - 8);   // CU pairs (15-k, k): uniform work/CU
    int b = g >> 4, h = g & 15;
    int t = threadIdx.x, w = t >> 6, l = t & 63, lg = l >> 4, lr = l & 15;
    const u16* base = qkv + (size_t)b * S_ * T3_;
    const u16* vbase = Vt + (size_t)g * 64 * S_;
    int prow = w * 16 + lr;          // local P row (wave-private slab, 0..127)
    int qb = qt * 128;
    int qrow = qb + w * 16 + lr;     // this lane's q (column of S^T)

    // staging: 512 threads x 2 passes cover one 128x64 K tile + 64x128 V tile
    auto stage = [&](int kt2, int bs) {
        int kb2 = kt2 * 128;
#pragma unroll
        for (int p = 0; p < 2; ++p) {
            int slot = w * 128 + p * 64 + l;     // 0..1023
            int ubase = (w * 128 + p * 64) * 8;  // u16 units, wave-uniform
            int rowK = slot >> 3, ckK = (slot & 7) ^ (rowK & 7);
            gload_lds16(base + (size_t)(kb2 + rowK) * T3_ + NX_ + h * 64 + ckK * 8,
                        &k_lds[bs][ubase]);
            int rowV = slot >> 4, ckV = (slot & 15) ^ (rowV & 7);
            gload_lds16(vbase + (size_t)rowV * S_ + kb2 + ckV * 8,
                        &v_lds[bs][ubase]);
        }
    };

    f32x4 zero4 = {0.f, 0.f, 0.f, 0.f};

    bf16x8 qf[2];
#pragma unroll
    for (int ks = 0; ks < 2; ++ks)
        qf[ks] = *reinterpret_cast<const bf16x8*>(
            base + (size_t)qrow * T3_ + h * 64 + ks * 32 + lg * 8);

    f32x4 oacc[4];
#pragma unroll
    for (int dc = 0; dc < 4; ++dc) oacc[dc] = zero4;
    float mrun = -1e30f, lrun = 0.f;
    int nkt = qt + 1;                // 128-wide kv tiles

    stage(0, 0);
    __syncthreads();

    for (int kt = 0; kt < nkt; ++kt) {
        int cur = kt & 1;
        if (kt + 1 < nkt) stage(kt + 1, cur ^ 1);   // issue early; drains at end barrier

        int kb = kt * 128;
        // S^T = K Q^T : lane holds S[k = kb+kn*16+lg*4+r][q = qrow] (log2 units)
        f32x4 sacc[8];
#pragma unroll
        for (int kn = 0; kn < 8; ++kn) sacc[kn] = zero4;
        __builtin_amdgcn_s_setprio(1);
#pragma unroll
        for (int ks = 0; ks < 2; ++ks) {
#pragma unroll
            for (int kn = 0; kn < 8; ++kn) {
                bf16x8 kf = *reinterpret_cast<const bf16x8*>(
                    &k_lds[cur][(kn * 16 + lr) * 64 + (((ks * 4 + lg) ^ (lr & 7)) * 8)]);
                sacc[kn] = __builtin_amdgcn_mfma_f32_16x16x32_bf16(
                    kf, qf[ks], sacc[kn], 0, 0, 0);
            }
        }
        __builtin_amdgcn_s_setprio(0);

        if (kt == qt) {   // diagonal tile: causal mask (kv > q), per element
#pragma unroll
            for (int kn = 0; kn < 8; ++kn)
#pragma unroll
                for (int r = 0; r < 4; ++r)
                    if (kb + kn * 16 + lg * 4 + r > qrow) sacc[kn][r] = -1e30f;
        }

        // in-register online softmax over 128 kv (log2 domain)
        float mx = -1e30f;
#pragma unroll
        for (int kn = 0; kn < 8; ++kn) {
            float a0 = fmaxf(sacc[kn][0], sacc[kn][1]);
            float a1 = fmaxf(sacc[kn][2], sacc[kn][3]);
            mx = fmaxf(mx, fmaxf(a0, a1));
        }
        mx = fmaxf(mx, __shfl_xor(mx, 16));
        mx = fmaxf(mx, __shfl_xor(mx, 32));

        bool noresc = __all(mx <= mrun + 1.5f);   // defer-max: P <= 2^1.5 = 2.83
        float mnew = noresc ? mrun : fmaxf(mrun, mx);

        float rs = 0.f;
#pragma unroll
        for (int kn = 0; kn < 8; ++kn)
#pragma unroll
            for (int r = 0; r < 4; ++r) {
                float pv = exp2f(sacc[kn][r] - mnew);
                sacc[kn][r] = pv;
                rs += pv;
            }
        rs += __shfl_xor(rs, 16);
        rs += __shfl_xor(rs, 32);

        if (noresc) {
            lrun += rs;
        } else {
            float fsc = exp2f(mrun - mnew);
            mrun = mnew;
            lrun = lrun * fsc + rs;
            float f0 = __shfl(fsc, lg * 4 + 0);
            float f1 = __shfl(fsc, lg * 4 + 1);
            float f2 = __shfl(fsc, lg * 4 + 2);
            float f3 = __shfl(fsc, lg * 4 + 3);
#pragma unroll
            for (int dc = 0; dc < 4; ++dc) {
                oacc[dc][0] *= f0; oacc[dc][1] *= f1;
                oacc[dc][2] *= f2; oacc[dc][3] *= f3;
            }
        }

        // PV in two 64-kv half-passes through the wave-private P slab
#pragma unroll
        for (int half = 0; half < 2; ++half) {
#pragma unroll
            for (int kn2 = 0; kn2 < 4; ++kn2) {
                int kn = half * 4 + kn2;
                bf16x4 pb;
                pb[0] = (__bf16)sacc[kn][0]; pb[1] = (__bf16)sacc[kn][1];
                pb[2] = (__bf16)sacc[kn][2]; pb[3] = (__bf16)sacc[kn][3];
                int byteoff = prow * 128 + (((2 * kn2 + (lg >> 1)) ^ (prow & 7)) * 16) + (lg & 1) * 8;
                *reinterpret_cast<bf16x4*>(reinterpret_cast<char*>(p_lds) + byteoff) = pb;
            }
            __builtin_amdgcn_s_setprio(1);
#pragma unroll
            for (int ks2 = 0; ks2 < 2; ++ks2) {
                bf16x8 pf = *reinterpret_cast<const bf16x8*>(
                    reinterpret_cast<char*>(p_lds) + prow * 128 + (((ks2 * 4 + lg) ^ (prow & 7)) * 16));
#pragma unroll
                for (int dc = 0; dc < 4; ++dc) {
                    bf16x8 vf = *reinterpret_cast<const bf16x8*>(
                        &v_lds[cur][(dc * 16 + lr) * 128 +
                                    (((half * 8 + ks2 * 4 + lg) ^ (lr & 7)) * 8)]);
                    oacc[dc] = __builtin_amdgcn_mfma_f32_16x16x32_bf16(
                        pf, vf, oacc[dc], 0, 0, 0);
                }
            }
            __builtin_amdgcn_s_setprio(0);
        }
        __syncthreads();   // single barrier/tile: k/v_lds[cur] reads done before restage
    }

    // epilogue: O /= l ; store bf16 [token][h*64+d]
    float inv = 1.f / lrun;
    float i0 = __shfl(inv, lg * 4 + 0);
    float i1 = __shfl(inv, lg * 4 + 1);
    float i2 = __shfl(inv, lg * 4 + 2);
    float i3 = __shfl(inv, lg * 4 + 3);
    u16* ob = outa + (size_t)b * S_ * NX_;
#pragma unroll
    for (int r = 0; r < 4; ++r) {
        float ir = (r == 0) ? i0 : (r == 1) ? i1 : (r == 2) ? i2 : i3;
        int row = qb + w * 16 + lg * 4 + r;
#pragma unroll
        for (int dc = 0; dc < 4; ++dc)
            ob[(size_t)row * NX_ + h * 64 + dc * 16 + lr] = bfbits(oacc[dc][r] * ir);
    }
}

extern "C" void kernel_launch(void* const* d_in, const int* in_sizes, int n_in,
                              void* d_out, int out_size, void* d_ws, size_t ws_size,
                              hipStream_t stream) {
    const float* x        = (const float*)d_in[0];
    const float* c_attn_w = (const float*)d_in[1];
    const float* c_attn_b = (const float*)d_in[2];
    const float* c_proj_w = (const float*)d_in[3];
    const float* c_proj_b = (const float*)d_in[4];
    float* out = (float*)d_out;

    u16* xb     = (u16*)d_ws;                         // [4096][1024] bf16  (8 MB)
    u16* wqkvT  = xb + (size_t)M_ * NX_;              // [3072][1024] bf16  (6 MB)
    u16* wprojT = wqkvT + (size_t)T3_ * NX_;          // [1024][1024] bf16  (2 MB)
    u16* qkv    = wprojT + (size_t)NX_ * NX_;         // [4096][3072] bf16  (24 MB; V part unused)
    u16* attno  = xb;                                 // reuse xb after GEMM1 (8 MB)
    u16* Vtp    = (u16*)d_out;                        // scratch: Vt 8 MB inside 16 MB out;
                                                      // fully overwritten by GEMM2 at the end

    // 1) fused prep: x -> bf16, both weights -> transposed bf16 (one launch)
    prep_kernel<<<8192, 256, 0, stream>>>(x, xb, c_attn_w, wqkvT, c_proj_w, wprojT);
    // 2) qkv = x @ c_attn_w + b (bf16, Q pre-scaled, 8-wave GEMM); V-part -> Vtp
    gemm_bt_kernel<<<(M_ / BM) * (T3_ / BN), 512, 0, stream>>>(
        xb, wqkvT, c_attn_b, qkv, nullptr, Vtp, 2 * NX_, NX_, M_, T3_, NX_);
    // 3) attention (8-wave blocks, q-tile 128, KVBLK 128, 512 blocks)
    attn_kernel<<<512, 512, 0, stream>>>(qkv, Vtp, attno);
    // 4) out = attn @ c_proj_w + b  (f32 out, BN=64 GEMM: 512 blocks = 2/CU)
    gemm_bt64_kernel<<<(M_ / BM) * (NX_ / 64), 512, 0, stream>>>(
        attno, wprojT, c_proj_b, out, M_, NX_, NX_);
}